// Round 1
// baseline (67.917 us; speedup 1.0000x reference)
//
#include <hip/hip_runtime.h>

#define BSZ 2
#define LEN 2048
#define DIM 1024
#define NST 16

// ---------------------------------------------------------------------------
// Pass 1: per-chunk local scan with H0 = 0.
// Records per-chunk decay P[n] = prod(A_bar) and local final H[n].
// Thread = (b, chunk k, d). Lanes = consecutive d -> coalesced X/delta loads.
// ---------------------------------------------------------------------------
template <int NC>
__global__ __launch_bounds__(256) void ssm_pass1(
    const float* __restrict__ Xp, const float* __restrict__ Bp,
    const float* __restrict__ dp, const float* __restrict__ Alog,
    float* __restrict__ wsP, float* __restrict__ wsH)
{
    constexpr int CL = LEN / NC;
    const int d   = (blockIdx.x % (DIM / 256)) * 256 + threadIdx.x;
    const int rem = blockIdx.x / (DIM / 256);
    const int k   = rem % NC;
    const int b   = rem / NC;

    // A[n] = -exp(A_log[d][n]); invA = 1/A  (A strictly negative -> safe)
    float A[NST], invA[NST];
    const float4* Ar = reinterpret_cast<const float4*>(Alog + (size_t)d * NST);
#pragma unroll
    for (int j = 0; j < 4; ++j) {
        float4 t = Ar[j];
        float v0 = -__expf(t.x), v1 = -__expf(t.y);
        float v2 = -__expf(t.z), v3 = -__expf(t.w);
        A[4*j+0] = v0; A[4*j+1] = v1; A[4*j+2] = v2; A[4*j+3] = v3;
        invA[4*j+0] = 1.0f / v0; invA[4*j+1] = 1.0f / v1;
        invA[4*j+2] = 1.0f / v2; invA[4*j+3] = 1.0f / v3;
    }

    float H[NST], P[NST];
#pragma unroll
    for (int n = 0; n < NST; ++n) { H[n] = 0.0f; P[n] = 1.0f; }

    size_t off = ((size_t)(b * LEN + k * CL)) * DIM + d;
    const float* Brow = Bp + (size_t)(b * LEN + k * CL) * NST;

    for (int l = 0; l < CL; ++l) {
        const float dv = dp[off];
        const float xv = Xp[off];
        float Bv[NST];
#pragma unroll
        for (int j = 0; j < 4; ++j) {
            float4 t = reinterpret_cast<const float4*>(Brow)[j];
            Bv[4*j+0] = t.x; Bv[4*j+1] = t.y; Bv[4*j+2] = t.z; Bv[4*j+3] = t.w;
        }
#pragma unroll
        for (int n = 0; n < NST; ++n) {
            const float e = __expf(dv * A[n]);
            const float c = xv * invA[n] * Bv[n];
            const float u = __builtin_fmaf(c, e, -c);   // c*(e-1)
            H[n] = __builtin_fmaf(e, H[n], u);
            P[n] *= e;
        }
        off  += DIM;
        Brow += NST;
    }

    const size_t wbase = ((size_t)(b * NC + k)) * NST;
#pragma unroll
    for (int n = 0; n < NST; ++n) {
        const size_t idx = (wbase + n) * DIM + d;
        wsP[idx] = P[n];
        wsH[idx] = H[n];
    }
}

// ---------------------------------------------------------------------------
// Pass 2: scan across chunks for each (b,d,n).
// In-place: wsH[k] is replaced by the chunk-START state for chunk k.
// Final state (= reference H_final) goes to d_out.
// ---------------------------------------------------------------------------
__global__ __launch_bounds__(256) void ssm_pass2(
    const float* __restrict__ wsP, float* __restrict__ wsH,
    float* __restrict__ Hfin, int NC)
{
    const int lin = blockIdx.x * 256 + threadIdx.x;   // B*N*D threads
    const int d   = lin % DIM;
    const int rem = lin / DIM;
    const int n   = rem % NST;
    const int b   = rem / NST;

    float h = 0.0f;
    for (int k = 0; k < NC; ++k) {
        const size_t idx = (((size_t)(b * NC + k)) * NST + n) * DIM + d;
        const float p  = wsP[idx];
        const float hl = wsH[idx];
        wsH[idx] = h;                         // start state for chunk k
        h = __builtin_fmaf(p, h, hl);
    }
    Hfin[((size_t)b * DIM + d) * NST + n] = h;
}

// ---------------------------------------------------------------------------
// Pass 3: recompute within-chunk scan from the true start state, emit Y.
// ---------------------------------------------------------------------------
template <int NC>
__global__ __launch_bounds__(256) void ssm_pass3(
    const float* __restrict__ Xp, const float* __restrict__ Bp,
    const float* __restrict__ Cp, const float* __restrict__ dp,
    const float* __restrict__ Alog, const float* __restrict__ wsHs,
    float* __restrict__ Yp)
{
    constexpr int CL = LEN / NC;
    const int d   = (blockIdx.x % (DIM / 256)) * 256 + threadIdx.x;
    const int rem = blockIdx.x / (DIM / 256);
    const int k   = rem % NC;
    const int b   = rem / NC;

    float A[NST], invA[NST];
    const float4* Ar = reinterpret_cast<const float4*>(Alog + (size_t)d * NST);
#pragma unroll
    for (int j = 0; j < 4; ++j) {
        float4 t = Ar[j];
        float v0 = -__expf(t.x), v1 = -__expf(t.y);
        float v2 = -__expf(t.z), v3 = -__expf(t.w);
        A[4*j+0] = v0; A[4*j+1] = v1; A[4*j+2] = v2; A[4*j+3] = v3;
        invA[4*j+0] = 1.0f / v0; invA[4*j+1] = 1.0f / v1;
        invA[4*j+2] = 1.0f / v2; invA[4*j+3] = 1.0f / v3;
    }

    float H[NST];
#pragma unroll
    for (int n = 0; n < NST; ++n)
        H[n] = wsHs[(((size_t)(b * NC + k)) * NST + n) * DIM + d];

    size_t off = ((size_t)(b * LEN + k * CL)) * DIM + d;
    const float* Brow = Bp + (size_t)(b * LEN + k * CL) * NST;
    const float* Crow = Cp + (size_t)(b * LEN + k * CL) * NST;

    for (int l = 0; l < CL; ++l) {
        const float dv = dp[off];
        const float xv = Xp[off];
        float Bv[NST], Cv[NST];
#pragma unroll
        for (int j = 0; j < 4; ++j) {
            float4 t = reinterpret_cast<const float4*>(Brow)[j];
            Bv[4*j+0] = t.x; Bv[4*j+1] = t.y; Bv[4*j+2] = t.z; Bv[4*j+3] = t.w;
            float4 s = reinterpret_cast<const float4*>(Crow)[j];
            Cv[4*j+0] = s.x; Cv[4*j+1] = s.y; Cv[4*j+2] = s.z; Cv[4*j+3] = s.w;
        }
        float y = 0.0f;
#pragma unroll
        for (int n = 0; n < NST; ++n) {
            const float e = __expf(dv * A[n]);
            const float c = xv * invA[n] * Bv[n];
            const float u = __builtin_fmaf(c, e, -c);
            H[n] = __builtin_fmaf(e, H[n], u);
            y = __builtin_fmaf(Cv[n], H[n], y);
        }
        Yp[off] = y;
        off  += DIM;
        Brow += NST;
        Crow += NST;
    }
}

// ---------------------------------------------------------------------------
template <int NC>
static void launch_all(const float* X, const float* Bm, const float* Cm,
                       const float* dl, const float* Alog,
                       float* wsP, float* wsH,
                       float* Hfin, float* Yout, hipStream_t stream)
{
    const int blocks13 = BSZ * NC * (DIM / 256);
    const int blocks2  = (BSZ * NST * DIM) / 256;
    ssm_pass1<NC><<<blocks13, 256, 0, stream>>>(X, Bm, dl, Alog, wsP, wsH);
    ssm_pass2<<<blocks2, 256, 0, stream>>>(wsP, wsH, Hfin, NC);
    ssm_pass3<NC><<<blocks13, 256, 0, stream>>>(X, Bm, Cm, dl, Alog, wsH, Yout);
}

extern "C" void kernel_launch(void* const* d_in, const int* in_sizes, int n_in,
                              void* d_out, int out_size, void* d_ws, size_t ws_size,
                              hipStream_t stream)
{
    const float* X    = (const float*)d_in[0];
    const float* Bm   = (const float*)d_in[1];
    const float* Cm   = (const float*)d_in[2];
    const float* dl   = (const float*)d_in[3];
    const float* Alog = (const float*)d_in[4];

    float* Hfin = (float*)d_out;                       // [B,D,N]  (first output)
    float* Yout = (float*)d_out + (size_t)BSZ * DIM * NST;  // [B,L,D]

    // ws layout: wsP then wsH, each B*NC*N*D floats
    auto need = [](int nc) -> size_t {
        return 2ull * sizeof(float) * BSZ * nc * NST * DIM;
    };

    if (ws_size >= need(64)) {
        float* wsP = (float*)d_ws;
        float* wsH = wsP + (size_t)BSZ * 64 * NST * DIM;
        launch_all<64>(X, Bm, Cm, dl, Alog, wsP, wsH, Hfin, Yout, stream);
    } else if (ws_size >= need(32)) {
        float* wsP = (float*)d_ws;
        float* wsH = wsP + (size_t)BSZ * 32 * NST * DIM;
        launch_all<32>(X, Bm, Cm, dl, Alog, wsP, wsH, Hfin, Yout, stream);
    } else if (ws_size >= need(16)) {
        float* wsP = (float*)d_ws;
        float* wsH = wsP + (size_t)BSZ * 16 * NST * DIM;
        launch_all<16>(X, Bm, Cm, dl, Alog, wsP, wsH, Hfin, Yout, stream);
    } else if (ws_size >= need(8)) {
        float* wsP = (float*)d_ws;
        float* wsH = wsP + (size_t)BSZ * 8 * NST * DIM;
        launch_all<8>(X, Bm, Cm, dl, Alog, wsP, wsH, Hfin, Yout, stream);
    } else {
        float* wsP = (float*)d_ws;
        float* wsH = wsP + (size_t)BSZ * 2 * NST * DIM;
        launch_all<2>(X, Bm, Cm, dl, Alog, wsP, wsH, Hfin, Yout, stream);
    }
}

// Round 2
// 53.362 us; speedup vs baseline: 1.2728x; 1.2728x over previous
//
#include <hip/hip_runtime.h>

#define BSZ 2
#define LEN 2048
#define DIM 1024
#define NST 16

// Scaled-state formulation: S[n] = (-A[n]) * H[n]  (A = -exp(A_log) < 0)
//   step:  e = exp2(A2[n]*dv);  m = x*B[n];  S = e*(S - m) + m
//   chunk decay: P[n] = exp2(A2[n] * sum(dv))        (A2 = A*log2(e))
//   output: H[n] = S[n] * exp(-A_log[n]) = S[n]*E[n]; y = sum C[n]*E[n]*S[n]

// ---------------------------------------------------------------------------
// Pass 1: per-chunk local scan with S0 = 0. Writes float2{P, S_local}.
// ---------------------------------------------------------------------------
template <int NC>
__global__ __launch_bounds__(256) void ssm_pass1(
    const float* __restrict__ Xp, const float* __restrict__ Bp,
    const float* __restrict__ dp, const float* __restrict__ Alog,
    float2* __restrict__ ws2)
{
    constexpr int CL = LEN / NC;
    const int d   = (blockIdx.x % (DIM / 256)) * 256 + threadIdx.x;
    const int rem = blockIdx.x / (DIM / 256);
    const int k   = rem % NC;
    const int b   = rem / NC;

    float A2[NST];
    const float4* Ar = reinterpret_cast<const float4*>(Alog + (size_t)d * NST);
#pragma unroll
    for (int j = 0; j < 4; ++j) {
        float4 t = Ar[j];
        A2[4*j+0] = -__expf(t.x) * 1.44269504f;
        A2[4*j+1] = -__expf(t.y) * 1.44269504f;
        A2[4*j+2] = -__expf(t.z) * 1.44269504f;
        A2[4*j+3] = -__expf(t.w) * 1.44269504f;
    }

    float S[NST];
#pragma unroll
    for (int n = 0; n < NST; ++n) S[n] = 0.0f;
    float dsum = 0.0f;

    size_t off = ((size_t)(b * LEN + k * CL)) * DIM + d;
    const float* Brow = Bp + (size_t)(b * LEN + k * CL) * NST;

#pragma unroll 4
    for (int l = 0; l < CL; ++l) {
        const float dv = dp[off];
        const float xv = Xp[off];
        dsum += dv;
        float Bv[NST];
#pragma unroll
        for (int j = 0; j < 4; ++j) {
            float4 t = reinterpret_cast<const float4*>(Brow)[j];
            Bv[4*j+0] = t.x; Bv[4*j+1] = t.y; Bv[4*j+2] = t.z; Bv[4*j+3] = t.w;
        }
#pragma unroll
        for (int n = 0; n < NST; ++n) {
            const float e = __builtin_amdgcn_exp2f(dv * A2[n]);
            const float m = xv * Bv[n];
            S[n] = __builtin_fmaf(e, S[n] - m, m);
        }
        off  += DIM;
        Brow += NST;
    }

    const size_t wbase = ((size_t)(b * NC + k)) * NST;
#pragma unroll
    for (int n = 0; n < NST; ++n) {
        const float P = __builtin_amdgcn_exp2f(A2[n] * dsum);
        ws2[(wbase + n) * DIM + d] = make_float2(P, S[n]);
    }
}

// ---------------------------------------------------------------------------
// Pass 2: scan across chunks for each (b,n,d). Writes chunk-START state to
// wsS, final H (converted back) to d_out.
// ---------------------------------------------------------------------------
template <int NC>
__global__ __launch_bounds__(256) void ssm_pass2(
    const float2* __restrict__ ws2, float* __restrict__ wsS,
    const float* __restrict__ Alog, float* __restrict__ Hfin)
{
    const int lin = blockIdx.x * 256 + threadIdx.x;   // B*N*D threads
    const int d   = lin % DIM;
    const int rem = lin / DIM;
    const int n   = rem % NST;
    const int b   = rem / NST;

    float s = 0.0f;
#pragma unroll 8
    for (int k = 0; k < NC; ++k) {
        const size_t idx = (((size_t)(b * NC + k)) * NST + n) * DIM + d;
        const float2 ph = ws2[idx];
        wsS[idx] = s;                         // start state for chunk k
        s = __builtin_fmaf(ph.x, s, ph.y);
    }
    const float E = __expf(-Alog[(size_t)d * NST + n]);
    Hfin[((size_t)b * DIM + d) * NST + n] = s * E;
}

// ---------------------------------------------------------------------------
// Pass 3: recompute within-chunk scan from the true start state, emit Y.
// ---------------------------------------------------------------------------
template <int NC>
__global__ __launch_bounds__(256) void ssm_pass3(
    const float* __restrict__ Xp, const float* __restrict__ Bp,
    const float* __restrict__ Cp, const float* __restrict__ dp,
    const float* __restrict__ Alog, const float* __restrict__ wsS,
    float* __restrict__ Yp)
{
    constexpr int CL = LEN / NC;
    const int d   = (blockIdx.x % (DIM / 256)) * 256 + threadIdx.x;
    const int rem = blockIdx.x / (DIM / 256);
    const int k   = rem % NC;
    const int b   = rem / NC;

    float A2[NST], E[NST];
    const float4* Ar = reinterpret_cast<const float4*>(Alog + (size_t)d * NST);
#pragma unroll
    for (int j = 0; j < 4; ++j) {
        float4 t = Ar[j];
        A2[4*j+0] = -__expf(t.x) * 1.44269504f;
        A2[4*j+1] = -__expf(t.y) * 1.44269504f;
        A2[4*j+2] = -__expf(t.z) * 1.44269504f;
        A2[4*j+3] = -__expf(t.w) * 1.44269504f;
        E[4*j+0] = __expf(-t.x);
        E[4*j+1] = __expf(-t.y);
        E[4*j+2] = __expf(-t.z);
        E[4*j+3] = __expf(-t.w);
    }

    float S[NST];
#pragma unroll
    for (int n = 0; n < NST; ++n)
        S[n] = wsS[(((size_t)(b * NC + k)) * NST + n) * DIM + d];

    size_t off = ((size_t)(b * LEN + k * CL)) * DIM + d;
    const float* Brow = Bp + (size_t)(b * LEN + k * CL) * NST;
    const float* Crow = Cp + (size_t)(b * LEN + k * CL) * NST;

#pragma unroll 4
    for (int l = 0; l < CL; ++l) {
        const float dv = dp[off];
        const float xv = Xp[off];
        float Bv[NST], Cv[NST];
#pragma unroll
        for (int j = 0; j < 4; ++j) {
            float4 t = reinterpret_cast<const float4*>(Brow)[j];
            Bv[4*j+0] = t.x; Bv[4*j+1] = t.y; Bv[4*j+2] = t.z; Bv[4*j+3] = t.w;
            float4 s4 = reinterpret_cast<const float4*>(Crow)[j];
            Cv[4*j+0] = s4.x; Cv[4*j+1] = s4.y; Cv[4*j+2] = s4.z; Cv[4*j+3] = s4.w;
        }
        float y = 0.0f;
#pragma unroll
        for (int n = 0; n < NST; ++n) {
            const float e = __builtin_amdgcn_exp2f(dv * A2[n]);
            const float m = xv * Bv[n];
            S[n] = __builtin_fmaf(e, S[n] - m, m);
            y = __builtin_fmaf(Cv[n] * E[n], S[n], y);
        }
        Yp[off] = y;
        off  += DIM;
        Brow += NST;
        Crow += NST;
    }
}

// ---------------------------------------------------------------------------
template <int NC>
static void launch_all(const float* X, const float* Bm, const float* Cm,
                       const float* dl, const float* Alog,
                       float2* ws2, float* wsS,
                       float* Hfin, float* Yout, hipStream_t stream)
{
    const int blocks13 = BSZ * NC * (DIM / 256);
    const int blocks2  = (BSZ * NST * DIM) / 256;
    ssm_pass1<NC><<<blocks13, 256, 0, stream>>>(X, Bm, dl, Alog, ws2);
    ssm_pass2<NC><<<blocks2, 256, 0, stream>>>(ws2, wsS, Alog, Hfin);
    ssm_pass3<NC><<<blocks13, 256, 0, stream>>>(X, Bm, Cm, dl, Alog, wsS, Yout);
}

extern "C" void kernel_launch(void* const* d_in, const int* in_sizes, int n_in,
                              void* d_out, int out_size, void* d_ws, size_t ws_size,
                              hipStream_t stream)
{
    const float* X    = (const float*)d_in[0];
    const float* Bm   = (const float*)d_in[1];
    const float* Cm   = (const float*)d_in[2];
    const float* dl   = (const float*)d_in[3];
    const float* Alog = (const float*)d_in[4];

    float* Hfin = (float*)d_out;                            // [B,D,N]
    float* Yout = (float*)d_out + (size_t)BSZ * DIM * NST;  // [B,L,D]

    // ws layout: ws2 (float2 x B*NC*N*D) then wsS (float x B*NC*N*D)
    auto need = [](int nc) -> size_t {
        return 3ull * sizeof(float) * BSZ * nc * NST * DIM;
    };

    if (ws_size >= need(128)) {
        float2* ws2 = (float2*)d_ws;
        float*  wsS = (float*)(ws2 + (size_t)BSZ * 128 * NST * DIM);
        launch_all<128>(X, Bm, Cm, dl, Alog, ws2, wsS, Hfin, Yout, stream);
    } else if (ws_size >= need(64)) {
        float2* ws2 = (float2*)d_ws;
        float*  wsS = (float*)(ws2 + (size_t)BSZ * 64 * NST * DIM);
        launch_all<64>(X, Bm, Cm, dl, Alog, ws2, wsS, Hfin, Yout, stream);
    } else if (ws_size >= need(32)) {
        float2* ws2 = (float2*)d_ws;
        float*  wsS = (float*)(ws2 + (size_t)BSZ * 32 * NST * DIM);
        launch_all<32>(X, Bm, Cm, dl, Alog, ws2, wsS, Hfin, Yout, stream);
    } else {
        float2* ws2 = (float2*)d_ws;
        float*  wsS = (float*)(ws2 + (size_t)BSZ * 8 * NST * DIM);
        launch_all<8>(X, Bm, Cm, dl, Alog, ws2, wsS, Hfin, Yout, stream);
    }
}